// Round 16
// baseline (194.576 us; speedup 1.0000x reference)
//
#include <hip/hip_runtime.h>

#define BB 4
#define CC 256
#define HH 128
#define WW 128
#define NN (HH*WW)
#define EPSF 1e-10f

// padded NHWC bf16 x: [b][row 0..129][col 0..129][ic 0..255], data at row/col 1..128
#define XR 130
#define XPB ((size_t)XR*XR*CC)

typedef __bf16 bf16x8 __attribute__((ext_vector_type(8)));
typedef float  f32x4  __attribute__((ext_vector_type(4)));
typedef float  f32x16 __attribute__((ext_vector_type(16)));

__device__ __forceinline__ float delu_f(float v) {
    // x>0: 10x+1 ; x<=0: exp(10x)
    return v > 0.0f ? fmaf(10.0f, v, 1.0f) : __expf(10.0f * v);
}

// async global->LDS, 16B per lane: LDS dest = base + lane*16 (linear), global src per-lane
__device__ __forceinline__ void gl_lds16(const __bf16* g, __bf16* l) {
    __builtin_amdgcn_global_load_lds(
        (const __attribute__((address_space(1))) void*)g,
        (__attribute__((address_space(3))) void*)l, 16, 0, 0);
}

// ---------------- weight packs, 32x32x16-fragment-linear (R15-verified layout):
// wpk32[gks 0..15][ocf32 0..7][lane 0..63][e 0..7]:
//   lane = khi*32 + (oc&31), gks = ic>>4, khi = (ic>>3)&1, e = ic&7
// conv: wcv32[t 0..8][...same...], wd1 folded into t=4
__global__ __launch_bounds__(256) void k_prep(const float* __restrict__ wq,
    const float* __restrict__ wk, const float* __restrict__ wv,
    const float* __restrict__ wd1, const float* __restrict__ wd3,
    __bf16* __restrict__ wqb, __bf16* __restrict__ wkb, __bf16* __restrict__ wvb,
    __bf16* __restrict__ wcv32)
{
    int idx = blockIdx.x * 256 + threadIdx.x;   // oc*256+ic
    if (idx >= CC*CC) return;
    const int oc = idx >> 8, ic = idx & 255;
    const int ocf32 = oc >> 5;
    const int gks = ic >> 4, khi = (ic >> 3) & 1;
    const int lane32 = khi*32 + (oc & 31);
    const int e = ic & 7;
    const size_t off32 = ((size_t)(gks*8 + ocf32)*64 + lane32)*8 + e;
    wqb[off32] = (__bf16)wq[idx];
    wkb[off32] = (__bf16)wk[idx];
    wvb[off32] = (__bf16)wv[idx];
    float w9[9];
    #pragma unroll
    for (int k=0;k<9;k++) w9[k] = wd3[(size_t)idx*9 + k];
    w9[4] += wd1[idx];
    #pragma unroll
    for (int t=0;t<9;t++) wcv32[(size_t)t*CC*CC + off32] = (__bf16)w9[t];
}

// ---------------- xpad: NCHW fp32 -> padded NHWC bf16
__global__ __launch_bounds__(256) void k_xpad(const float* __restrict__ x,
                                              __bf16* __restrict__ xpad)
{
    const int xrow = blockIdx.x;            // 0..129
    const int b    = blockIdx.y;
    const int tid  = threadIdx.x;
    const int hr   = xrow - 1;
    const float* xb = x + (size_t)b*CC*NN;
    __bf16* xpb = xpad + (size_t)b*XPB + (size_t)xrow*XR*CC;
    const bool rowok = (hr >= 0 && hr < HH);
    for (int t = tid; t < XR*32; t += 256) {
        int xcol = t % XR, icg = t / XR;
        int wc = xcol - 1;
        bf16x8 v8 = {};
        if (rowok && wc >= 0 && wc < WW) {
            const float* p = xb + (size_t)(icg*8)*NN + hr*WW + wc;
            #pragma unroll
            for (int j=0;j<8;j++) v8[j] = (__bf16)p[(size_t)j*NN];
        }
        *(bf16x8*)&xpb[(size_t)xcol*CC + icg*8] = v8;
    }
}

// ---------------- stage 128n x 256ic tile (one image row): xs[kq 0..31][n 0..131(132 pad)][ic8]
__device__ __forceinline__ void stage_row128(const __bf16* __restrict__ xrb,
                                             __bf16* __restrict__ xs,
                                             int wid, int lane)
{
    #pragma unroll
    for (int j = 0; j < 16; ++j) {
        const int it = wid + 4*j;
        const int kq = it >> 1, ch = it & 1;
        gl_lds16(xrb + (size_t)(ch*64 + lane)*CC + kq*8, &xs[(size_t)(kq*132 + ch*64)*8]);
    }
}

// ---------------- 64oc x 128n x 256ic GEMM via 32x32x16; A from packed wb (L2), B from LDS xs
__device__ __forceinline__ void mfma_gemm32(const __bf16* __restrict__ wb,
                                            const __bf16* __restrict__ xs,
                                            int wid, int lane, int l31, int lhi,
                                            f32x16 acc[2][4])
{
    #pragma unroll
    for (int kb=0; kb<8; kb++) {
        bf16x8 af[4];
        #pragma unroll
        for (int f=0; f<2; f++)
            #pragma unroll
            for (int kk=0; kk<2; kk++)
                af[f*2+kk] = *(const bf16x8*)&wb[((size_t)((kb*2+kk)*8 + wid*2 + f)*64 + lane)*8];
        #pragma unroll
        for (int kk=0; kk<2; kk++)
            #pragma unroll
            for (int nf=0; nf<4; nf++) {
                bf16x8 br = *(const bf16x8*)&xs[(size_t)((kb*4 + kk*2 + lhi)*132 + nf*32 + l31)*8];
                #pragma unroll
                for (int f=0; f<2; f++)
                    acc[f][nf] = __builtin_amdgcn_mfma_f32_32x32x16_bf16(af[f*2+kk], br, acc[f][nf], 0, 0, 0);
            }
    }
}

// ---------------- q'/k' projections via 32x32 MFMA + Qs = sum_m delu(q); k' -> kp (bf16)
// block: 256 oc x 128 n (one image row); wave = 64 oc x 128 n
__global__ __launch_bounds__(256) void k_qk_mfma(const __bf16* __restrict__ xpad,
    const __bf16* __restrict__ wqb, const float* __restrict__ bq,
    const __bf16* __restrict__ wkb, const float* __restrict__ bk,
    __bf16* __restrict__ kp, float* __restrict__ Qs)
{
    __shared__ __bf16 xs[32*132*8];
    __shared__ float Qpart[4][128];
    const int h  = blockIdx.x;
    const int n0 = h * 128;
    const int b  = blockIdx.y;
    const int tid = threadIdx.x;
    const int wid = tid >> 6, lane = tid & 63;
    const int l31 = lane & 31, lhi = lane >> 5;
    const int oc_base = wid*64;
    const __bf16* xrb = xpad + (size_t)b*XPB + ((size_t)(h+1)*XR + 1)*CC;

    stage_row128(xrb, xs, wid, lane);
    __syncthreads();

    // --- Q phase ---
    f32x16 acc[2][4] = {};
    mfma_gemm32(wqb, xs, wid, lane, l31, lhi, acc);
    #pragma unroll
    for (int nf=0; nf<4; nf++) {
        float s = 0.0f;
        #pragma unroll
        for (int f=0; f<2; f++)
            #pragma unroll
            for (int reg=0; reg<16; reg++) {
                const int oc = oc_base + f*32 + (reg&3) + 8*(reg>>2) + 4*lhi;
                s += delu_f(acc[f][nf][reg] + bq[oc]);
            }
        s += __shfl_xor(s, 32);
        if (lhi == 0) Qpart[wid][nf*32 + l31] = s;
    }
    __syncthreads();
    if (tid < 128)
        Qs[(size_t)b*NN + n0 + tid] = Qpart[0][tid] + Qpart[1][tid] + Qpart[2][tid] + Qpart[3][tid];

    // --- K phase ---
    #pragma unroll
    for (int f=0; f<2; f++)
        #pragma unroll
        for (int nf=0; nf<4; nf++)
            acc[f][nf] = (f32x16){};
    mfma_gemm32(wkb, xs, wid, lane, l31, lhi, acc);
    #pragma unroll
    for (int f=0; f<2; f++) {
        #pragma unroll
        for (int reg=0; reg<16; reg++) {
            const int oc = oc_base + f*32 + (reg&3) + 8*(reg>>2) + 4*lhi;
            const float bias = bk[oc];
            __bf16* kr = kp + ((size_t)b*CC + oc)*NN + n0;
            #pragma unroll
            for (int nf=0; nf<4; nf++)
                kr[nf*32 + l31] = (__bf16)delu_f(acc[f][nf][reg] + bias);
        }
    }
}

// ---------------- Esum[b,c] = sum_n Qs[b,n] * k'[b,c,n]
__global__ __launch_bounds__(256) void k_esum(const __bf16* __restrict__ kp,
    const float* __restrict__ Qs, float* __restrict__ Es)
{
    const int c = blockIdx.x & (CC-1), b = blockIdx.x >> 8;
    const int tid = threadIdx.x;
    const bf16x8* kr = (const bf16x8*)(kp + ((size_t)b*CC + c)*NN);
    const float4* qr = (const float4*)(Qs + (size_t)b*NN);
    float s = 0.0f;
    for (int i = tid; i < NN/8; i += 256) {
        bf16x8 kk = kr[i];
        float4 q0 = qr[2*i], q1 = qr[2*i+1];
        s += (float)kk[0]*q0.x + (float)kk[1]*q0.y + (float)kk[2]*q0.z + (float)kk[3]*q0.w
           + (float)kk[4]*q1.x + (float)kk[5]*q1.y + (float)kk[6]*q1.z + (float)kk[7]*q1.w;
    }
    #pragma unroll
    for (int m=1; m<64; m<<=1) s += __shfl_xor(s, m, 64);
    __shared__ float red[4];
    if ((tid & 63) == 0) red[tid >> 6] = s;
    __syncthreads();
    if (tid == 0) Es[b*CC + c] = red[0] + red[1] + red[2] + red[3];
}

// ---------------- v projection via 32x32 MFMA + in-block denom + attention epilogue
__global__ __launch_bounds__(256) void k_vattn_mfma(const float* __restrict__ x,
    const __bf16* __restrict__ xpad,
    const __bf16* __restrict__ wvb, const float* __restrict__ bv,
    const __bf16* __restrict__ kp, const float* __restrict__ Es,
    const float* __restrict__ gamma, float* __restrict__ out)
{
    __shared__ __bf16 xs[32*132*8];
    __shared__ float Dpart[4][128];
    __shared__ float rn_sh[128];
    const int h  = blockIdx.x;
    const int n0 = h * 128;
    const int b  = blockIdx.y;
    const int tid = threadIdx.x;
    const int wid = tid >> 6, lane = tid & 63;
    const int l31 = lane & 31, lhi = lane >> 5;
    const int oc_base = wid*64;
    const __bf16* xrb = xpad + (size_t)b*XPB + ((size_t)(h+1)*XR + 1)*CC;

    stage_row128(xrb, xs, wid, lane);
    __syncthreads();

    f32x16 acc[2][4] = {};
    mfma_gemm32(wvb, xs, wid, lane, l31, lhi, acc);

    // denom partials: sum over this wave's 64 oc of Es[oc]*k'[oc][n]
    float dpart[4] = {0.f,0.f,0.f,0.f};
    #pragma unroll
    for (int f=0; f<2; f++) {
        #pragma unroll
        for (int reg=0; reg<16; reg++) {
            const int oc = oc_base + f*32 + (reg&3) + 8*(reg>>2) + 4*lhi;
            const float e = Es[b*CC + oc];
            const __bf16* kr = kp + ((size_t)b*CC + oc)*NN + n0;
            #pragma unroll
            for (int nf=0; nf<4; nf++)
                dpart[nf] = fmaf(e, (float)kr[nf*32 + l31], dpart[nf]);
        }
    }
    #pragma unroll
    for (int nf=0; nf<4; nf++) {
        dpart[nf] += __shfl_xor(dpart[nf], 32);
        if (lhi == 0) Dpart[wid][nf*32 + l31] = dpart[nf];
    }
    __syncthreads();
    if (tid < 128)
        rn_sh[tid] = 1.0f / (Dpart[0][tid] + Dpart[1][tid] + Dpart[2][tid] + Dpart[3][tid] + EPSF);
    __syncthreads();

    const float g = gamma[0];
    #pragma unroll
    for (int f=0; f<2; f++) {
        #pragma unroll
        for (int reg=0; reg<16; reg++) {
            const int oc = oc_base + f*32 + (reg&3) + 8*(reg>>2) + 4*lhi;
            const float eg = Es[b*CC + oc] * g;
            const float bias = bv[oc];
            const __bf16* kr = kp + ((size_t)b*CC + oc)*NN + n0;
            const float* xr  = x  + ((size_t)b*CC + oc)*NN + n0;
            float* orow = out + ((size_t)b*CC + oc)*NN + n0;
            #pragma unroll
            for (int nf=0; nf<4; nf++) {
                const int w = nf*32 + l31;
                orow[w] = fmaf(eg*(float)kr[w]*rn_sh[w], acc[f][nf][reg] + bias, xr[w]);
            }
        }
    }
}

// ---------------- 3x3 conv (+folded 1x1) via 32x32x16 MFMA (R15-proven, unchanged):
// block 256 thr = 4 waves; wave = 64 oc (2 ocf32) x 128 cols; block = 256 oc x 1 row.
__global__ __launch_bounds__(256,2) void k_conv_mfma(const __bf16* __restrict__ xpad,
    const __bf16* __restrict__ wcv32, const float* __restrict__ bd1,
    const float* __restrict__ bd3, const float* __restrict__ gamma,
    float* __restrict__ out)
{
    __shared__ __bf16 xs[2][12*132*8];
    // bijective XCD swizzle: nwg=512, 64 per XCD -> contiguous h-band per XCD
    const int orig = blockIdx.x;
    const int wg   = (orig & 7)*64 + (orig >> 3);
    const int b    = wg >> 7;
    const int h    = wg & 127;
    const int tid = threadIdx.x;
    const int wid = tid >> 6, lane = tid & 63;
    const int l31 = lane & 31, lhi = lane >> 5;
    const int oc_base = wid*64;
    const __bf16* xpb = xpad + (size_t)b*XPB;

    f32x16 acc[2][4] = {};

    #define STAGE_CV(bufsel, icb) do {                                          \
        const int ic0_ = (icb)*32;                                              \
        _Pragma("unroll")                                                       \
        for (int j = 0; j < 9; ++j) {                                           \
            const int w_ = wid + 4*j;                                           \
            const int pair_ = w_ / 3, chunk_ = w_ % 3;                          \
            const int r_ = pair_ >> 2, icq_ = pair_ & 3;                        \
            const int col0_ = chunk_ * 64;                                      \
            if (col0_ + lane < XR)                                              \
                gl_lds16(xpb + ((size_t)(h + r_)*XR + col0_ + lane)*CC + ic0_ + icq_*8, \
                         &xs[bufsel][(size_t)(pair_*132 + col0_)*8]);           \
        }                                                                       \
    } while (0)

    #define AF_LOAD(dst, t, icb)                                                \
        _Pragma("unroll")                                                       \
        for (int f=0; f<2; f++)                                                 \
            _Pragma("unroll")                                                   \
            for (int kk=0; kk<2; kk++)                                          \
                dst[f*2+kk] = *(const bf16x8*)&wcv32[((size_t)(t)*CC*CC) +      \
                    ((size_t)((((icb)*2 + kk)*8 + wid*2 + f))*64 + lane)*8];

    STAGE_CV(0, 0);
    __syncthreads();

    #pragma unroll 1
    for (int icb = 0; icb < 8; ++icb) {
        bf16x8 af2[2][4];
        AF_LOAD(af2[0], 0, icb);
        if (icb < 7) STAGE_CV((icb+1)&1, icb+1);
        #pragma unroll
        for (int t=0; t<9; ++t) {
            const int cur = t & 1, nxt = cur ^ 1;
            const int ky = t/3, kx = t%3;
            if (t < 8) { AF_LOAD(af2[nxt], t+1, icb); }
            __builtin_amdgcn_s_setprio(1);
            #pragma unroll
            for (int kk=0; kk<2; kk++) {
                #pragma unroll
                for (int nf=0; nf<4; nf++) {
                    bf16x8 br = *(const bf16x8*)&xs[icb & 1][
                        (size_t)((ky*4 + kk*2 + lhi)*132 + nf*32 + l31 + kx)*8];
                    #pragma unroll
                    for (int f=0; f<2; f++)
                        acc[f][nf] = __builtin_amdgcn_mfma_f32_32x32x16_bf16(
                            af2[cur][f*2+kk], br, acc[f][nf], 0, 0, 0);
                }
            }
            __builtin_amdgcn_s_setprio(0);
        }
        __syncthreads();
    }
    #undef STAGE_CV
    #undef AF_LOAD

    const float g = gamma[0];
    #pragma unroll
    for (int f=0; f<2; f++) {
        #pragma unroll
        for (int reg=0; reg<16; reg++) {
            const int row = (reg & 3) + 8*(reg >> 2) + 4*lhi;
            const int oc = oc_base + f*32 + row;
            const float bias = bd1[oc] + bd3[oc];
            float* orow = out + ((size_t)b*CC + oc)*NN + (size_t)h*WW;
            #pragma unroll
            for (int nf=0; nf<4; nf++) {
                const int w = nf*32 + l31;
                orow[w] += g*(acc[f][nf][reg] + bias);
            }
        }
    }
}

extern "C" void kernel_launch(void* const* d_in, const int* in_sizes, int n_in,
                              void* d_out, int out_size, void* d_ws, size_t ws_size,
                              hipStream_t stream)
{
    const float* x     = (const float*)d_in[0];
    const float* wq    = (const float*)d_in[1];
    const float* bq    = (const float*)d_in[2];
    const float* wk    = (const float*)d_in[3];
    const float* bk    = (const float*)d_in[4];
    const float* wv    = (const float*)d_in[5];
    const float* bv    = (const float*)d_in[6];
    const float* wd1   = (const float*)d_in[7];
    const float* bd1   = (const float*)d_in[8];
    const float* wd3   = (const float*)d_in[9];
    const float* bd3   = (const float*)d_in[10];
    const float* gamma = (const float*)d_in[11];
    float* out = (float*)d_out;

    __bf16* kp    = (__bf16*)d_ws;                    // B*C*N bf16 (33.5 MB)
    float*  Qs    = (float*)(kp + (size_t)BB*CC*NN);  // B*N
    float*  Es    = Qs + (size_t)BB*NN;               // B*C
    __bf16* wcv32 = (__bf16*)(Es + (size_t)BB*CC);    // [9][256][256] bf16, 32x32-fragment-linear
    __bf16* wqb   = wcv32 + (size_t)9*CC*CC;          // [256][256] bf16, 32x32-fragment-linear
    __bf16* wkb   = wqb + (size_t)CC*CC;
    __bf16* wvb   = wkb + (size_t)CC*CC;
    __bf16* xpad  = wvb + (size_t)CC*CC;              // [4][130][130][256] bf16 (34.6 MB)

    k_prep      <<<dim3(CC*CC/256), 256, 0, stream>>>(wq, wk, wv, wd1, wd3, wqb, wkb, wvb, wcv32);
    k_xpad      <<<dim3(XR, BB), 256, 0, stream>>>(x, xpad);
    k_qk_mfma   <<<dim3(HH, BB), 256, 0, stream>>>(xpad, wqb, bq, wkb, bk, kp, Qs);
    k_esum      <<<dim3(BB*CC), 256, 0, stream>>>(kp, Qs, Es);
    k_vattn_mfma<<<dim3(HH, BB), 256, 0, stream>>>(x, xpad, wvb, bv, kp, Es, gamma, out);
    k_conv_mfma <<<dim3(HH*BB), 256, 0, stream>>>(xpad, wcv32, bd1, bd3, gamma, out);
}

// Round 17
// 190.760 us; speedup vs baseline: 1.0200x; 1.0200x over previous
//
#include <hip/hip_runtime.h>

#define BB 4
#define CC 256
#define HH 128
#define WW 128
#define NN (HH*WW)
#define EPSF 1e-10f

// padded NHWC bf16 x: [b][row 0..129][col 0..129][ic 0..255], data at row/col 1..128
#define XR 130
#define XPB ((size_t)XR*XR*CC)

typedef __bf16 bf16x8 __attribute__((ext_vector_type(8)));
typedef float  f32x4  __attribute__((ext_vector_type(4)));
typedef float  f32x16 __attribute__((ext_vector_type(16)));

__device__ __forceinline__ float delu_f(float v) {
    // x>0: 10x+1 ; x<=0: exp(10x)
    return v > 0.0f ? fmaf(10.0f, v, 1.0f) : __expf(10.0f * v);
}

// async global->LDS, 16B per lane: LDS dest = base + lane*16 (linear), global src per-lane
__device__ __forceinline__ void gl_lds16(const __bf16* g, __bf16* l) {
    __builtin_amdgcn_global_load_lds(
        (const __attribute__((address_space(1))) void*)g,
        (__attribute__((address_space(3))) void*)l, 16, 0, 0);
}

// ---------------- weight packs, 32x32x16-fragment-linear (R15-verified layout):
// wpk32[gks 0..15][ocf32 0..7][lane 0..63][e 0..7]:
//   lane = khi*32 + (oc&31), gks = ic>>4, khi = (ic>>3)&1, e = ic&7
// conv: wcv32[t 0..8][...same...], wd1 folded into t=4
__global__ __launch_bounds__(256) void k_prep(const float* __restrict__ wq,
    const float* __restrict__ wk, const float* __restrict__ wv,
    const float* __restrict__ wd1, const float* __restrict__ wd3,
    __bf16* __restrict__ wqb, __bf16* __restrict__ wkb, __bf16* __restrict__ wvb,
    __bf16* __restrict__ wcv32)
{
    int idx = blockIdx.x * 256 + threadIdx.x;   // oc*256+ic
    if (idx >= CC*CC) return;
    const int oc = idx >> 8, ic = idx & 255;
    const int ocf32 = oc >> 5;
    const int gks = ic >> 4, khi = (ic >> 3) & 1;
    const int lane32 = khi*32 + (oc & 31);
    const int e = ic & 7;
    const size_t off32 = ((size_t)(gks*8 + ocf32)*64 + lane32)*8 + e;
    wqb[off32] = (__bf16)wq[idx];
    wkb[off32] = (__bf16)wk[idx];
    wvb[off32] = (__bf16)wv[idx];
    float w9[9];
    #pragma unroll
    for (int k=0;k<9;k++) w9[k] = wd3[(size_t)idx*9 + k];
    w9[4] += wd1[idx];
    #pragma unroll
    for (int t=0;t<9;t++) wcv32[(size_t)t*CC*CC + off32] = (__bf16)w9[t];
}

// ---------------- xpad: NCHW fp32 -> padded NHWC bf16
__global__ __launch_bounds__(256) void k_xpad(const float* __restrict__ x,
                                              __bf16* __restrict__ xpad)
{
    const int xrow = blockIdx.x;            // 0..129
    const int b    = blockIdx.y;
    const int tid  = threadIdx.x;
    const int hr   = xrow - 1;
    const float* xb = x + (size_t)b*CC*NN;
    __bf16* xpb = xpad + (size_t)b*XPB + (size_t)xrow*XR*CC;
    const bool rowok = (hr >= 0 && hr < HH);
    for (int t = tid; t < XR*32; t += 256) {
        int xcol = t % XR, icg = t / XR;
        int wc = xcol - 1;
        bf16x8 v8 = {};
        if (rowok && wc >= 0 && wc < WW) {
            const float* p = xb + (size_t)(icg*8)*NN + hr*WW + wc;
            #pragma unroll
            for (int j=0;j<8;j++) v8[j] = (__bf16)p[(size_t)j*NN];
        }
        *(bf16x8*)&xpb[(size_t)xcol*CC + icg*8] = v8;
    }
}

// ---------------- stage 128n x 256ic tile (one image row): xs[kq 0..31][n 0..131(132 pad)][ic8]
__device__ __forceinline__ void stage_row128(const __bf16* __restrict__ xrb,
                                             __bf16* __restrict__ xs,
                                             int wid, int lane)
{
    #pragma unroll
    for (int j = 0; j < 16; ++j) {
        const int it = wid + 4*j;
        const int kq = it >> 1, ch = it & 1;
        gl_lds16(xrb + (size_t)(ch*64 + lane)*CC + kq*8, &xs[(size_t)(kq*132 + ch*64)*8]);
    }
}

// ---------------- 64oc x 128n x 256ic GEMM via 32x32x16; A from packed wb (L2), B from LDS xs
__device__ __forceinline__ void mfma_gemm32(const __bf16* __restrict__ wb,
                                            const __bf16* __restrict__ xs,
                                            int wid, int lane, int l31, int lhi,
                                            f32x16 acc[2][4])
{
    #pragma unroll
    for (int kb=0; kb<8; kb++) {
        bf16x8 af[4];
        #pragma unroll
        for (int f=0; f<2; f++)
            #pragma unroll
            for (int kk=0; kk<2; kk++)
                af[f*2+kk] = *(const bf16x8*)&wb[((size_t)((kb*2+kk)*8 + wid*2 + f)*64 + lane)*8];
        #pragma unroll
        for (int kk=0; kk<2; kk++)
            #pragma unroll
            for (int nf=0; nf<4; nf++) {
                bf16x8 br = *(const bf16x8*)&xs[(size_t)((kb*4 + kk*2 + lhi)*132 + nf*32 + l31)*8];
                #pragma unroll
                for (int f=0; f<2; f++)
                    acc[f][nf] = __builtin_amdgcn_mfma_f32_32x32x16_bf16(af[f*2+kk], br, acc[f][nf], 0, 0, 0);
            }
    }
}

// ---------------- q'/k' projections via 32x32 MFMA + Qs = sum_m delu(q); k' -> kp (bf16)
__global__ __launch_bounds__(256) void k_qk_mfma(const __bf16* __restrict__ xpad,
    const __bf16* __restrict__ wqb, const float* __restrict__ bq,
    const __bf16* __restrict__ wkb, const float* __restrict__ bk,
    __bf16* __restrict__ kp, float* __restrict__ Qs)
{
    __shared__ __bf16 xs[32*132*8];
    __shared__ float Qpart[4][128];
    const int h  = blockIdx.x;
    const int n0 = h * 128;
    const int b  = blockIdx.y;
    const int tid = threadIdx.x;
    const int wid = tid >> 6, lane = tid & 63;
    const int l31 = lane & 31, lhi = lane >> 5;
    const int oc_base = wid*64;
    const __bf16* xrb = xpad + (size_t)b*XPB + ((size_t)(h+1)*XR + 1)*CC;

    stage_row128(xrb, xs, wid, lane);
    __syncthreads();

    // --- Q phase ---
    f32x16 acc[2][4] = {};
    mfma_gemm32(wqb, xs, wid, lane, l31, lhi, acc);
    #pragma unroll
    for (int nf=0; nf<4; nf++) {
        float s = 0.0f;
        #pragma unroll
        for (int f=0; f<2; f++)
            #pragma unroll
            for (int reg=0; reg<16; reg++) {
                const int oc = oc_base + f*32 + (reg&3) + 8*(reg>>2) + 4*lhi;
                s += delu_f(acc[f][nf][reg] + bq[oc]);
            }
        s += __shfl_xor(s, 32);
        if (lhi == 0) Qpart[wid][nf*32 + l31] = s;
    }
    __syncthreads();
    if (tid < 128)
        Qs[(size_t)b*NN + n0 + tid] = Qpart[0][tid] + Qpart[1][tid] + Qpart[2][tid] + Qpart[3][tid];

    // --- K phase ---
    #pragma unroll
    for (int f=0; f<2; f++)
        #pragma unroll
        for (int nf=0; nf<4; nf++)
            acc[f][nf] = (f32x16){};
    mfma_gemm32(wkb, xs, wid, lane, l31, lhi, acc);
    #pragma unroll
    for (int f=0; f<2; f++) {
        #pragma unroll
        for (int reg=0; reg<16; reg++) {
            const int oc = oc_base + f*32 + (reg&3) + 8*(reg>>2) + 4*lhi;
            const float bias = bk[oc];
            __bf16* kr = kp + ((size_t)b*CC + oc)*NN + n0;
            #pragma unroll
            for (int nf=0; nf<4; nf++)
                kr[nf*32 + l31] = (__bf16)delu_f(acc[f][nf][reg] + bias);
        }
    }
}

// ---------------- Esum[b,c] = sum_n Qs[b,n] * k'[b,c,n]
__global__ __launch_bounds__(256) void k_esum(const __bf16* __restrict__ kp,
    const float* __restrict__ Qs, float* __restrict__ Es)
{
    const int c = blockIdx.x & (CC-1), b = blockIdx.x >> 8;
    const int tid = threadIdx.x;
    const bf16x8* kr = (const bf16x8*)(kp + ((size_t)b*CC + c)*NN);
    const float4* qr = (const float4*)(Qs + (size_t)b*NN);
    float s = 0.0f;
    for (int i = tid; i < NN/8; i += 256) {
        bf16x8 kk = kr[i];
        float4 q0 = qr[2*i], q1 = qr[2*i+1];
        s += (float)kk[0]*q0.x + (float)kk[1]*q0.y + (float)kk[2]*q0.z + (float)kk[3]*q0.w
           + (float)kk[4]*q1.x + (float)kk[5]*q1.y + (float)kk[6]*q1.z + (float)kk[7]*q1.w;
    }
    #pragma unroll
    for (int m=1; m<64; m<<=1) s += __shfl_xor(s, m, 64);
    __shared__ float red[4];
    if ((tid & 63) == 0) red[tid >> 6] = s;
    __syncthreads();
    if (tid == 0) Es[b*CC + c] = red[0] + red[1] + red[2] + red[3];
}

// ---------------- 3x3 conv (+folded 1x1) via 32x32x16 MFMA (R15-proven loop):
// epilogue now writes convout (bf16) = conv + bd1 + bd3  -- NO out RMW
__global__ __launch_bounds__(256,2) void k_conv_mfma(const __bf16* __restrict__ xpad,
    const __bf16* __restrict__ wcv32, const float* __restrict__ bd1,
    const float* __restrict__ bd3, __bf16* __restrict__ convout)
{
    __shared__ __bf16 xs[2][12*132*8];
    // bijective XCD swizzle: nwg=512, 64 per XCD -> contiguous h-band per XCD
    const int orig = blockIdx.x;
    const int wg   = (orig & 7)*64 + (orig >> 3);
    const int b    = wg >> 7;
    const int h    = wg & 127;
    const int tid = threadIdx.x;
    const int wid = tid >> 6, lane = tid & 63;
    const int l31 = lane & 31, lhi = lane >> 5;
    const int oc_base = wid*64;
    const __bf16* xpb = xpad + (size_t)b*XPB;

    f32x16 acc[2][4] = {};

    #define STAGE_CV(bufsel, icb) do {                                          \
        const int ic0_ = (icb)*32;                                              \
        _Pragma("unroll")                                                       \
        for (int j = 0; j < 9; ++j) {                                           \
            const int w_ = wid + 4*j;                                           \
            const int pair_ = w_ / 3, chunk_ = w_ % 3;                          \
            const int r_ = pair_ >> 2, icq_ = pair_ & 3;                        \
            const int col0_ = chunk_ * 64;                                      \
            if (col0_ + lane < XR)                                              \
                gl_lds16(xpb + ((size_t)(h + r_)*XR + col0_ + lane)*CC + ic0_ + icq_*8, \
                         &xs[bufsel][(size_t)(pair_*132 + col0_)*8]);           \
        }                                                                       \
    } while (0)

    #define AF_LOAD(dst, t, icb)                                                \
        _Pragma("unroll")                                                       \
        for (int f=0; f<2; f++)                                                 \
            _Pragma("unroll")                                                   \
            for (int kk=0; kk<2; kk++)                                          \
                dst[f*2+kk] = *(const bf16x8*)&wcv32[((size_t)(t)*CC*CC) +      \
                    ((size_t)((((icb)*2 + kk)*8 + wid*2 + f))*64 + lane)*8];

    STAGE_CV(0, 0);
    __syncthreads();

    #pragma unroll 1
    for (int icb = 0; icb < 8; ++icb) {
        bf16x8 af2[2][4];
        AF_LOAD(af2[0], 0, icb);
        if (icb < 7) STAGE_CV((icb+1)&1, icb+1);
        #pragma unroll
        for (int t=0; t<9; ++t) {
            const int cur = t & 1, nxt = cur ^ 1;
            const int ky = t/3, kx = t%3;
            if (t < 8) { AF_LOAD(af2[nxt], t+1, icb); }
            __builtin_amdgcn_s_setprio(1);
            #pragma unroll
            for (int kk=0; kk<2; kk++) {
                #pragma unroll
                for (int nf=0; nf<4; nf++) {
                    bf16x8 br = *(const bf16x8*)&xs[icb & 1][
                        (size_t)((ky*4 + kk*2 + lhi)*132 + nf*32 + l31 + kx)*8];
                    #pragma unroll
                    for (int f=0; f<2; f++)
                        acc[f][nf] = __builtin_amdgcn_mfma_f32_32x32x16_bf16(
                            af2[cur][f*2+kk], br, acc[f][nf], 0, 0, 0);
                }
            }
            __builtin_amdgcn_s_setprio(0);
        }
        __syncthreads();
    }
    #undef STAGE_CV
    #undef AF_LOAD

    #pragma unroll
    for (int f=0; f<2; f++) {
        #pragma unroll
        for (int reg=0; reg<16; reg++) {
            const int row = (reg & 3) + 8*(reg >> 2) + 4*lhi;
            const int oc = oc_base + f*32 + row;
            const float bias = bd1[oc] + bd3[oc];
            __bf16* orow = convout + ((size_t)b*CC + oc)*NN + (size_t)h*WW;
            #pragma unroll
            for (int nf=0; nf<4; nf++) {
                const int w = nf*32 + l31;
                orow[w] = (__bf16)(acc[f][nf][reg] + bias);
            }
        }
    }
}

// ---------------- v projection via 32x32 MFMA + in-block denom + FINAL fused epilogue:
// out = x(from LDS xs, bf16) + g*(Es*k'*rn*(v+bv) + convout)
__global__ __launch_bounds__(256) void k_vattn_mfma(
    const __bf16* __restrict__ xpad,
    const __bf16* __restrict__ wvb, const float* __restrict__ bv,
    const __bf16* __restrict__ kp, const float* __restrict__ Es,
    const __bf16* __restrict__ convout,
    const float* __restrict__ gamma, float* __restrict__ out)
{
    __shared__ __bf16 xs[32*132*8];
    __shared__ float Dpart[4][128];
    __shared__ float rn_sh[128];
    const int h  = blockIdx.x;
    const int n0 = h * 128;
    const int b  = blockIdx.y;
    const int tid = threadIdx.x;
    const int wid = tid >> 6, lane = tid & 63;
    const int l31 = lane & 31, lhi = lane >> 5;
    const int oc_base = wid*64;
    const __bf16* xrb = xpad + (size_t)b*XPB + ((size_t)(h+1)*XR + 1)*CC;

    stage_row128(xrb, xs, wid, lane);
    __syncthreads();

    f32x16 acc[2][4] = {};
    mfma_gemm32(wvb, xs, wid, lane, l31, lhi, acc);

    // denom partials: sum over this wave's 64 oc of Es[oc]*k'[oc][n]
    float dpart[4] = {0.f,0.f,0.f,0.f};
    #pragma unroll
    for (int f=0; f<2; f++) {
        #pragma unroll
        for (int reg=0; reg<16; reg++) {
            const int oc = oc_base + f*32 + (reg&3) + 8*(reg>>2) + 4*lhi;
            const float e = Es[b*CC + oc];
            const __bf16* kr = kp + ((size_t)b*CC + oc)*NN + n0;
            #pragma unroll
            for (int nf=0; nf<4; nf++)
                dpart[nf] = fmaf(e, (float)kr[nf*32 + l31], dpart[nf]);
        }
    }
    #pragma unroll
    for (int nf=0; nf<4; nf++) {
        dpart[nf] += __shfl_xor(dpart[nf], 32);
        if (lhi == 0) Dpart[wid][nf*32 + l31] = dpart[nf];
    }
    __syncthreads();
    if (tid < 128)
        rn_sh[tid] = 1.0f / (Dpart[0][tid] + Dpart[1][tid] + Dpart[2][tid] + Dpart[3][tid] + EPSF);
    __syncthreads();

    const float g = gamma[0];
    #pragma unroll
    for (int f=0; f<2; f++) {
        #pragma unroll
        for (int reg=0; reg<16; reg++) {
            const int oc = oc_base + f*32 + (reg&3) + 8*(reg>>2) + 4*lhi;
            const float eg = Es[b*CC + oc] * g;
            const float bias = bv[oc];
            const __bf16* kr = kp + ((size_t)b*CC + oc)*NN + n0;
            const __bf16* cr = convout + ((size_t)b*CC + oc)*NN + n0;
            const __bf16* xr = &xs[(size_t)((oc >> 3)*132)*8 + (oc & 7)];
            float* orow = out + ((size_t)b*CC + oc)*NN + n0;
            #pragma unroll
            for (int nf=0; nf<4; nf++) {
                const int w = nf*32 + l31;
                const float attn = eg*(float)kr[w]*rn_sh[w]*(acc[f][nf][reg] + bias);
                const float xv = (float)xr[(size_t)w*8];
                orow[w] = xv + attn + g*(float)cr[w];
            }
        }
    }
}

extern "C" void kernel_launch(void* const* d_in, const int* in_sizes, int n_in,
                              void* d_out, int out_size, void* d_ws, size_t ws_size,
                              hipStream_t stream)
{
    const float* x     = (const float*)d_in[0];
    const float* wq    = (const float*)d_in[1];
    const float* bq    = (const float*)d_in[2];
    const float* wk    = (const float*)d_in[3];
    const float* bk    = (const float*)d_in[4];
    const float* wv    = (const float*)d_in[5];
    const float* bv    = (const float*)d_in[6];
    const float* wd1   = (const float*)d_in[7];
    const float* bd1   = (const float*)d_in[8];
    const float* wd3   = (const float*)d_in[9];
    const float* bd3   = (const float*)d_in[10];
    const float* gamma = (const float*)d_in[11];
    float* out = (float*)d_out;

    __bf16* kp    = (__bf16*)d_ws;                    // B*C*N bf16 (33.5 MB)
    __bf16* cvout = kp + (size_t)BB*CC*NN;            // B*C*N bf16 (33.5 MB)
    float*  Qs    = (float*)(cvout + (size_t)BB*CC*NN); // B*N
    float*  Es    = Qs + (size_t)BB*NN;               // B*C
    __bf16* wcv32 = (__bf16*)(Es + (size_t)BB*CC);    // [9][256][256] bf16, 32x32-fragment-linear
    __bf16* wqb   = wcv32 + (size_t)9*CC*CC;          // [256][256] bf16, 32x32-fragment-linear
    __bf16* wkb   = wqb + (size_t)CC*CC;
    __bf16* wvb   = wkb + (size_t)CC*CC;
    __bf16* xpad  = wvb + (size_t)CC*CC;              // [4][130][130][256] bf16 (34.6 MB)

    k_prep      <<<dim3(CC*CC/256), 256, 0, stream>>>(wq, wk, wv, wd1, wd3, wqb, wkb, wvb, wcv32);
    k_xpad      <<<dim3(XR, BB), 256, 0, stream>>>(x, xpad);
    k_qk_mfma   <<<dim3(HH, BB), 256, 0, stream>>>(xpad, wqb, bq, wkb, bk, kp, Qs);
    k_esum      <<<dim3(BB*CC), 256, 0, stream>>>(kp, Qs, Es);
    k_conv_mfma <<<dim3(HH*BB), 256, 0, stream>>>(xpad, wcv32, bd1, bd3, cvout);
    k_vattn_mfma<<<dim3(HH, BB), 256, 0, stream>>>(xpad, wvb, bv, kp, Es, cvout, gamma, out);
}